// Round 5
// baseline (424.817 us; speedup 1.0000x reference)
//
#include <hip/hip_runtime.h>
#include <math.h>

// LinformerAttention on MI355X — Round 11: GEMM restructured for 2 blocks/CU
// (128x256 tile, BK=32, 48 KiB LDS, 64x64 per wave -> acc 64 regs,
// __launch_bounds__(512,4)). Keeps R9/R10's fragment-linear zero-conflict
// LDS, counted-vmcnt prefetch (vmcnt(2) boundary), setprio, XCD swizzle,
// and identical k-accumulation order (bit-identical output).
// Mechanism: independent co-resident block fills barrier/drain stalls (m114).
// B=8 T=2048 C=1024 H=16 D=64 Kproj=128. ws ~180 MB.

constexpr int B_ = 8, T_ = 2048, C_ = 1024, H_ = 16, D_ = 64, KP = 128;
constexpr int M_ = B_ * T_;            // 16384
constexpr int C3 = 3 * C_;             // 3072
constexpr int K_ = C_;                 // GEMM K = 1024
constexpr int NT = K_ / 32;            // 32 K-tiles of 32
constexpr int TCH = 4;                 // proj t-chunks of 512

typedef __attribute__((ext_vector_type(8))) short bf16x8;   // 8 bf16 = 4 VGPR
typedef __attribute__((ext_vector_type(4))) float f32x4;

__device__ __forceinline__ unsigned short f2bf(float f) {
  unsigned u = __builtin_bit_cast(unsigned, f);
  u += 0x7FFFu + ((u >> 16) & 1u);     // round-to-nearest-even
  return (unsigned short)(u >> 16);
}
__device__ __forceinline__ float bf2f(unsigned short h) {
  unsigned u = ((unsigned)h) << 16;
  return __builtin_bit_cast(float, u);
}

#define GLOAD_LDS16(gptr, lptr)                                                \
  __builtin_amdgcn_global_load_lds(                                            \
      (const __attribute__((address_space(1))) void*)(gptr),                   \
      (__attribute__((address_space(3))) void*)(lptr), 16, 0, 0)

// ---------------------------------------------------------------------------
// fp32 -> bf16 (hi) cast, row-major. n4 = n/4.
// ---------------------------------------------------------------------------
__global__ __launch_bounds__(256) void cast_bf16(
    const float* __restrict__ in, unsigned short* __restrict__ hi, int n4)
{
  int i = blockIdx.x * 256 + threadIdx.x;
  if (i >= n4) return;
  const float4 v = reinterpret_cast<const float4*>(in)[i];
  ushort4 h;
  h.x = f2bf(v.x); h.y = f2bf(v.y); h.z = f2bf(v.z); h.w = f2bf(v.w);
  reinterpret_cast<ushort4*>(hi)[i] = h;
}

// ---------------------------------------------------------------------------
// Transpose + bf16: W [rows][cols] fp32 -> T [cols][rows] bf16.
// ---------------------------------------------------------------------------
__global__ __launch_bounds__(256) void cast_tr(
    const float* __restrict__ W, unsigned short* __restrict__ Tb,
    int rows, int cols)
{
  __shared__ float tile[32][33];
  const int c0 = blockIdx.x * 32, r0 = blockIdx.y * 32;
  const int tx = threadIdx.x & 31, ty = threadIdx.x >> 5;   // ty 0..7
  #pragma unroll
  for (int i = 0; i < 4; ++i)
    tile[ty + i * 8][tx] = W[(size_t)(r0 + ty + i * 8) * cols + c0 + tx];
  __syncthreads();
  #pragma unroll
  for (int i = 0; i < 4; ++i) {
    const int cr = ty + i * 8;
    Tb[(size_t)(c0 + cr) * rows + r0 + tx] = f2bf(tile[tx][cr]);
  }
}

// ---------------------------------------------------------------------------
// 128x256 GEMM, 2 blocks/CU: C(16384 x ldc) = A(MxK) @ BT^T + bias, K=1024.
// BT is [N][K] bf16. 512 threads = 8 waves (2wr x 4wc); per-wave 64x64 out.
// LDS 48 KiB: 2 buf x (A 8KB @0 + B 16KB @8192). BK=32 -> NT=32 tiles.
//
// Fragment-linear layout (zero bank conflicts, verified R9):
//   A frag fr (rows fr*16+c, k=q*8+e):  byte = fr*1024 + lane*16
//   B frag fn (cols fn*16+c):    byte = 8192 + fn*1024 + lane*16
// Per tile, 2 phases:
//  ph1: read av[0..3] (A, fr=wr*4+i) + bv[0,1] (fn=wc*4+{0,1}, region BH0);
//       stage BH1(t+1) -> other buf; bar; 8 MFMA (j=0,1); bar.
//  ph2: read bv[2,3] (fn=wc*4+{2,3}, region BH1);
//       stage A(t+2)+BH0(t+2) -> this buf; bar; 8 MFMA (j=2,3);
//       boundary vmcnt(2) (t<NT-2) / vmcnt(0) (t==NT-2); bar.
// Region stage-issue is >=1 full barrier after its read phase (race-free).
// Staging: per thread 3 gloads/tile, dest = wave-uniform base + lane*16.
// ---------------------------------------------------------------------------
template <bool BFOUT>
__global__ __launch_bounds__(512, 4) void gemm128(
    const unsigned short* __restrict__ A, const unsigned short* __restrict__ BT,
    const float* __restrict__ bias, float* __restrict__ Cf,
    unsigned short* __restrict__ Cb, int ldc)
{
  __shared__ __attribute__((aligned(16))) char lds[49152];

  const int tid  = threadIdx.x;
  const int lane = tid & 63;
  const int w    = tid >> 6;           // 0..7
  const int wr   = w >> 2;             // 0..1 (M)
  const int wc   = w & 3;              // 0..3 (N)
  const int col  = lane & 15;
  const int quad = lane >> 4;

  // T1: bijective XCD-chunked block swizzle (gridDim.x % 8 == 0 here).
  const int ntx = ldc >> 8;
  int wg = blockIdx.x;
  wg = (wg & 7) * (gridDim.x >> 3) + (wg >> 3);
  const int bx = wg % ntx, by = wg / ntx;
  const int m0 = by << 7, n0 = bx << 8;

  // --- staging geometry (3 gloads per thread per tile) ---
  const int kq   = quad * 8;                        // k sub-offset (elems)
  const int fnB0 = (w >> 1) * 4 + (w & 1);          // BH0 fragment (fn&3 < 2)
  const int fnB1 = fnB0 + 2;                        // BH1 fragment (fn&3 >= 2)
  const unsigned short* Asrc  = A  + (size_t)(m0 + w * 16 + col) * K_ + kq;
  const unsigned short* B0src = BT + (size_t)(n0 + fnB0 * 16 + col) * K_ + kq;
  const unsigned short* B1src = BT + (size_t)(n0 + fnB1 * 16 + col) * K_ + kq;
  const int dA  = w * 1024 + lane * 16;
  const int dB0 = 8192 + fnB0 * 1024 + lane * 16;
  const int dB1 = 8192 + fnB1 * 1024 + lane * 16;

#define STG_A(KT, BUF)  GLOAD_LDS16(Asrc  + (KT) * 32, lds + (BUF) * 24576 + dA)
#define STG_B0(KT, BUF) GLOAD_LDS16(B0src + (KT) * 32, lds + (BUF) * 24576 + dB0)
#define STG_B1(KT, BUF) GLOAD_LDS16(B1src + (KT) * 32, lds + (BUF) * 24576 + dB1)

  // --- ds_read fragment addressing: base + lane*16, fully linear ---
  const int laneB = lane * 16;
  const int aOff = wr * 4096 + laneB;               // + i*1024
  const int bOff = 8192 + wc * 4096 + laneB;        // + j*1024

  f32x4 acc[4][4];
  #pragma unroll
  for (int i = 0; i < 4; ++i)
    #pragma unroll
    for (int j = 0; j < 4; ++j)
      acc[i][j] = (f32x4){0.f, 0.f, 0.f, 0.f};

  bf16x8 av[4], bv[4];

  // --- prologue: tile0 fully + tile1 {A,BH0}; vmcnt(2) ---
  STG_A(0, 0); STG_B0(0, 0); STG_B1(0, 0);
  STG_A(1, 1); STG_B0(1, 1);
  asm volatile("s_waitcnt vmcnt(2)" ::: "memory");
  __builtin_amdgcn_s_barrier();

#define TILE(KT, CUR)                                                          \
  {                                                                            \
    const char* cb = lds + (CUR) * 24576;                                      \
    /* phase 1: read A + BH0; stage BH1(t+1); MFMA j=0,1 */                    \
    _Pragma("unroll")                                                          \
    for (int i = 0; i < 4; ++i)                                                \
      av[i] = *reinterpret_cast<const bf16x8*>(cb + aOff + i * 1024);          \
    bv[0] = *reinterpret_cast<const bf16x8*>(cb + bOff);                       \
    bv[1] = *reinterpret_cast<const bf16x8*>(cb + bOff + 1024);                \
    if ((KT) + 1 < NT) { STG_B1((KT) + 1, (CUR) ^ 1); }                        \
    __builtin_amdgcn_s_barrier();                                              \
    __builtin_amdgcn_s_setprio(1);                                             \
    _Pragma("unroll")                                                          \
    for (int j = 0; j < 2; ++j)                                                \
      _Pragma("unroll")                                                        \
      for (int i = 0; i < 4; ++i)                                              \
        acc[i][j] = __builtin_amdgcn_mfma_f32_16x16x32_bf16(                   \
            av[i], bv[j], acc[i][j], 0, 0, 0);                                 \
    __builtin_amdgcn_s_setprio(0);                                             \
    __builtin_amdgcn_s_barrier();                                              \
    /* phase 2: read BH1; stage A(t+2)+BH0(t+2); MFMA j=2,3; boundary */       \
    bv[2] = *reinterpret_cast<const bf16x8*>(cb + bOff + 2048);                \
    bv[3] = *reinterpret_cast<const bf16x8*>(cb + bOff + 3072);                \
    if ((KT) + 2 < NT) { STG_A((KT) + 2, (CUR)); STG_B0((KT) + 2, (CUR)); }    \
    __builtin_amdgcn_s_barrier();                                              \
    __builtin_amdgcn_s_setprio(1);                                             \
    _Pragma("unroll")                                                          \
    for (int j = 2; j < 4; ++j)                                                \
      _Pragma("unroll")                                                        \
      for (int i = 0; i < 4; ++i)                                              \
        acc[i][j] = __builtin_amdgcn_mfma_f32_16x16x32_bf16(                   \
            av[i], bv[j], acc[i][j], 0, 0, 0);                                 \
    __builtin_amdgcn_s_setprio(0);                                             \
    if ((KT) < NT - 2) {                                                       \
      asm volatile("s_waitcnt vmcnt(2)" ::: "memory");                         \
    } else if ((KT) == NT - 2) {                                               \
      asm volatile("s_waitcnt vmcnt(0)" ::: "memory");                         \
    }                                                                          \
    __builtin_amdgcn_s_barrier();                                              \
  }

  for (int kt = 0; kt < NT; kt += 2) {
    TILE(kt, 0);
    TILE(kt + 1, 1);
  }
#undef TILE
#undef STG_A
#undef STG_B0
#undef STG_B1

  // --- epilogue: C/D layout col=lane&15, row=quad*4+reg (session-verified) --
  #pragma unroll
  for (int i = 0; i < 4; ++i) {
    const int r = m0 + wr * 64 + i * 16 + quad * 4;
    #pragma unroll
    for (int j = 0; j < 4; ++j) {
      const int cc = n0 + wc * 64 + j * 16 + col;
      const float bvb = bias[cc];
      #pragma unroll
      for (int rg = 0; rg < 4; ++rg) {
        const float v = acc[i][j][rg] + bvb;
        const size_t o = (size_t)(r + rg) * ldc + cc;
        if constexpr (BFOUT) Cb[o] = f2bf(v);
        else Cf[o] = v;
      }
    }
  }
}

// ---------------------------------------------------------------------------
// MFMA proj (1-product): part[(bh*TCH+tc)][kk=128][d=64] fp32 =
//   sum_{t in 512-chunk} E[h][kk][t] * k[b*T+t][h*64+d]
// ---------------------------------------------------------------------------
__global__ __launch_bounds__(256) void proj_mfma(
    const unsigned short* __restrict__ Eh, const unsigned short* __restrict__ kb,
    int ldk, float* __restrict__ part)
{
  __shared__ unsigned short sE[KP * 72];           // 18.0 KB
  __shared__ unsigned short sK[D_ * 72];           //  9.0 KB

  const int bh = blockIdx.x;
  const int tc = blockIdx.y;
  const int b = bh >> 4, h = bh & 15;
  const int tid = threadIdx.x;
  const int lane = tid & 63;
  const int w = tid >> 6;
  const int col = lane & 15;
  const int quad = lane >> 4;
  const int tq = tid >> 4;            // 0..15 -> t-base tq*4
  const int dq = tid & 15;            // 0..15 -> d-base dq*4

  f32x4 acc[2][4];
  #pragma unroll
  for (int i = 0; i < 2; ++i)
    #pragma unroll
    for (int j = 0; j < 4; ++j) acc[i][j] = (f32x4){0.f, 0.f, 0.f, 0.f};

  for (int s = 0; s < 8; ++s) {
    const int t0 = tc * 512 + s * 64;
    #pragma unroll
    for (int l = 0; l < 4; ++l) {
      const int idx = l * 256 + tid;
      const int kk = idx >> 3, seg = idx & 7;
      *reinterpret_cast<uint4*>(sE + kk * 72 + seg * 8) =
          *reinterpret_cast<const uint4*>(
              Eh + (size_t)(h * KP + kk) * T_ + t0 + seg * 8);
    }
    {
      const size_t gbase = (size_t)(b * T_ + t0 + tq * 4) * ldk + h * D_ + dq * 4;
      ushort4 r[4];
      #pragma unroll
      for (int rr = 0; rr < 4; ++rr)
        r[rr] = *reinterpret_cast<const ushort4*>(kb + gbase + (size_t)rr * ldk);
      #pragma unroll
      for (int c = 0; c < 4; ++c) {
        ushort4 t;
        t.x = (&r[0].x)[c]; t.y = (&r[1].x)[c];
        t.z = (&r[2].x)[c]; t.w = (&r[3].x)[c];
        *reinterpret_cast<ushort4*>(sK + (dq * 4 + c) * 72 + tq * 4) = t;
      }
    }
    __syncthreads();

    bf16x8 av[2][2];
    #pragma unroll
    for (int i = 0; i < 2; ++i)
      #pragma unroll
      for (int ks = 0; ks < 2; ++ks)
        av[i][ks] = *reinterpret_cast<const bf16x8*>(
            sE + ((w * 2 + i) * 16 + col) * 72 + ks * 32 + quad * 8);
    #pragma unroll
    for (int j = 0; j < 4; ++j)
      #pragma unroll
      for (int ks = 0; ks < 2; ++ks) {
        const bf16x8 bv = *reinterpret_cast<const bf16x8*>(
            sK + (j * 16 + col) * 72 + ks * 32 + quad * 8);
        #pragma unroll
        for (int i = 0; i < 2; ++i)
          acc[i][j] = __builtin_amdgcn_mfma_f32_16x16x32_bf16(av[i][ks], bv, acc[i][j], 0, 0, 0);
      }
    __syncthreads();
  }

  float* op = part + ((size_t)bh * TCH + tc) * (KP * D_);
  #pragma unroll
  for (int i = 0; i < 2; ++i) {
    const int kkb = w * 32 + i * 16 + quad * 4;
    #pragma unroll
    for (int j = 0; j < 4; ++j) {
      const int d = j * 16 + col;
      #pragma unroll
      for (int rg = 0; rg < 4; ++rg)
        op[(kkb + rg) * D_ + d] = acc[i][j][rg];
    }
  }
}

// ---------------------------------------------------------------------------
// reduce_k: kprojh[bh][kk][d] (bf16) = sum_c part[bh][c][kk][d]
// ---------------------------------------------------------------------------
__global__ __launch_bounds__(256) void reduce_k(
    const float* __restrict__ part, unsigned short* __restrict__ kprojh)
{
  const int idx = blockIdx.x * 256 + threadIdx.x;   // over 128*8192
  const int bh = idx >> 13;
  const int i = idx & 8191;
  float s = 0.f;
  #pragma unroll
  for (int c = 0; c < TCH; ++c)
    s += part[((size_t)bh * TCH + c) * 8192 + i];
  kprojh[idx] = f2bf(s);
}

// ---------------------------------------------------------------------------
// reduce_v: vpT [bh][d][kk] bf16 = transpose(sum_c part[bh][c][kk][d])
// ---------------------------------------------------------------------------
__global__ __launch_bounds__(256) void reduce_v(
    const float* __restrict__ part, unsigned short* __restrict__ vpTh)
{
  __shared__ float sums[KP * 66];     // [kk][d] pitch 66
  const int bh = blockIdx.x;
  const int tid = threadIdx.x;
  #pragma unroll
  for (int j = 0; j < 32; ++j) {
    const int i = j * 256 + tid;      // kk = i>>6, d = i&63
    float s = 0.f;
    #pragma unroll
    for (int c = 0; c < TCH; ++c)
      s += part[((size_t)bh * TCH + c) * 8192 + i];
    sums[(i >> 6) * 66 + (i & 63)] = s;
  }
  __syncthreads();
  #pragma unroll
  for (int j = 0; j < 32; ++j) {
    const int i = j * 256 + tid;      // d = i>>7, kk = i&127
    vpTh[(size_t)bh * 8192 + i] = f2bf(sums[(i & 127) * 66 + (i >> 7)]);
  }
}

// ---------------------------------------------------------------------------
// MFMA attention (1-product): q bf16 from qkv[.., 0..C) (ld C3),
// kproj bf16 [kk][d], vpT bf16 [d][kk]; y bf16 out [M][C].
// ---------------------------------------------------------------------------
__global__ __launch_bounds__(256) void attn_mfma(
    const unsigned short* __restrict__ qkv, const unsigned short* __restrict__ kprojh,
    const unsigned short* __restrict__ vpTh, unsigned short* __restrict__ yh)
{
  // LDS union (35072 B): A: Qh@0(9216) Kp@9216(18432) end 27648
  //                      B: Vh@0(17408) Ps@17408(17408) atts@34816(256)
  __shared__ __attribute__((aligned(16))) char lds[35072];
  unsigned short* Qh = (unsigned short*)(lds);
  unsigned short* Kp = (unsigned short*)(lds + 9216);
  unsigned short* Vh = (unsigned short*)(lds);
  unsigned short* Ps = (unsigned short*)(lds + 17408);
  float* atts = (float*)(lds + 34816);

  const int tid  = threadIdx.x;
  const int lane = tid & 63;
  const int w    = tid >> 6;
  const int col  = lane & 15;
  const int quad = lane >> 4;
  const int bh = blockIdx.x >> 5;
  const int tch = blockIdx.x & 31;
  const int b = bh >> 4, h = bh & 15;
  const int t0 = tch * 64;

  { // stage Q (pitch 72) and Kp (pitch 72)
    const unsigned short* qg = qkv + (size_t)(b * T_ + t0) * C3 + h * D_;
    #pragma unroll
    for (int l = 0; l < 4; ++l) {
      const int idx = l * 256 + tid;
      const int t = idx >> 4, dc = (idx & 15) << 2;
      *reinterpret_cast<ushort4*>(Qh + t * 72 + dc) =
          *reinterpret_cast<const ushort4*>(qg + (size_t)t * C3 + dc);
    }
    const unsigned short* kg = kprojh + (size_t)bh * 8192;
    #pragma unroll
    for (int l = 0; l < 8; ++l) {
      const int idx = l * 256 + tid;
      const int kk = idx >> 4, dc = (idx & 15) << 2;
      *reinterpret_cast<ushort4*>(Kp + kk * 72 + dc) =
          *reinterpret_cast<const ushort4*>(kg + kk * 64 + dc);
    }
  }
  __syncthreads();

  // S^T = Kp(A) @ Q^T(B): m=kk (8 tiles), n=t (wave strip), k=d (2 steps)
  f32x4 s[8];
  #pragma unroll
  for (int i = 0; i < 8; ++i) s[i] = (f32x4){0.f, 0.f, 0.f, 0.f};
  bf16x8 bq[2];
  #pragma unroll
  for (int ks = 0; ks < 2; ++ks)
    bq[ks] = *reinterpret_cast<const bf16x8*>(
        Qh + (w * 16 + col) * 72 + ks * 32 + quad * 8);
  #pragma unroll
  for (int i = 0; i < 8; ++i)
    #pragma unroll
    for (int ks = 0; ks < 2; ++ks) {
      const bf16x8 a = *reinterpret_cast<const bf16x8*>(
          Kp + (i * 16 + col) * 72 + ks * 32 + quad * 8);
      s[i] = __builtin_amdgcn_mfma_f32_16x16x32_bf16(a, bq[ks], s[i], 0, 0, 0);
    }

  // softmax over kk (t = w*16+col)
  float mx = -3.0e38f;
  #pragma unroll
  for (int i = 0; i < 8; ++i)
    #pragma unroll
    for (int rg = 0; rg < 4; ++rg) {
      s[i][rg] *= 0.125f;
      mx = fmaxf(mx, s[i][rg]);
    }
  mx = fmaxf(mx, __shfl_xor(mx, 16));
  mx = fmaxf(mx, __shfl_xor(mx, 32));
  float sum = 0.f;
  #pragma unroll
  for (int i = 0; i < 8; ++i)
    #pragma unroll
    for (int rg = 0; rg < 4; ++rg) {
      const float e = __expf(s[i][rg] - mx);
      s[i][rg] = e;
      sum += e;
    }
  sum += __shfl_xor(sum, 16);
  sum += __shfl_xor(sum, 32);
  const float inv = 1.f / sum;
  __syncthreads();

  { // stage Vp (pitch 136)
    const unsigned short* vg = vpTh + (size_t)bh * 8192;
    #pragma unroll
    for (int l = 0; l < 8; ++l) {
      const int idx = l * 256 + tid;
      const int d = idx >> 5, kc = (idx & 31) << 2;
      *reinterpret_cast<ushort4*>(Vh + d * 136 + kc) =
          *reinterpret_cast<const ushort4*>(vg + d * 128 + kc);
    }
  }
  #pragma unroll
  for (int i = 0; i < 8; ++i) {
    ushort4 hp;
    hp.x = f2bf(s[i][0]); hp.y = f2bf(s[i][1]);
    hp.z = f2bf(s[i][2]); hp.w = f2bf(s[i][3]);
    *reinterpret_cast<ushort4*>(Ps + (w * 16 + col) * 136 + i * 16 + quad * 4) = hp;
  }
  if (quad == 0) atts[w * 16 + col] = inv;
  __syncthreads();

  // y = P(A) @ V(B): m=t (wave strip), n=d (4 tiles), k=kk (4 steps)
  f32x4 y[4];
  #pragma unroll
  for (int j = 0; j < 4; ++j) y[j] = (f32x4){0.f, 0.f, 0.f, 0.f};
  bf16x8 ap[4];
  #pragma unroll
  for (int ks = 0; ks < 4; ++ks)
    ap[ks] = *reinterpret_cast<const bf16x8*>(
        Ps + (w * 16 + col) * 136 + ks * 32 + quad * 8);
  #pragma unroll
  for (int j = 0; j < 4; ++j)
    #pragma unroll
    for (int ks = 0; ks < 4; ++ks) {
      const bf16x8 bv = *reinterpret_cast<const bf16x8*>(
          Vh + (j * 16 + col) * 136 + ks * 32 + quad * 8);
      y[j] = __builtin_amdgcn_mfma_f32_16x16x32_bf16(ap[ks], bv, y[j], 0, 0, 0);
    }

  const f32x4 inv4 = *reinterpret_cast<const f32x4*>(atts + w * 16 + quad * 4);
  #pragma unroll
  for (int j = 0; j < 4; ++j)
    #pragma unroll
    for (int rg = 0; rg < 4; ++rg) {
      const int t = t0 + w * 16 + quad * 4 + rg;
      const int d = j * 16 + col;
      yh[(size_t)(b * T_ + t) * C_ + h * D_ + d] = f2bf(y[j][rg] * inv4[rg]);
    }
}

// ---------------------------------------------------------------------------
extern "C" void kernel_launch(void* const* d_in, const int* in_sizes, int n_in,
                              void* d_out, int out_size, void* d_ws, size_t ws_size,
                              hipStream_t stream) {
  (void)in_sizes; (void)n_in; (void)out_size; (void)ws_size;
  const float* x      = (const float*)d_in[0];
  const float* W_attn = (const float*)d_in[1];
  const float* b_attn = (const float*)d_in[2];
  const float* W_proj = (const float*)d_in[3];
  const float* b_proj = (const float*)d_in[4];
  const float* E      = (const float*)d_in[5];
  const float* F      = (const float*)d_in[6];
  float* out = (float*)d_out;

  // ws regions, ~180.4 MB peak:
  unsigned short* xh   = (unsigned short*)d_ws;          // [M][C]  33.55 MB
  unsigned short* qkvh = xh + (size_t)M_ * C_;           // [M][3C] 100.66 MB
  unsigned short* WaT  = qkvh + (size_t)M_ * C3;         // [3072][1024] 6.29 MB
  unsigned short* WpT  = WaT + (size_t)C3 * C_;          // [1024][1024] 2.10 MB
  unsigned short* Eh   = WpT + (size_t)C_ * C_;          // 8.39 MB
  unsigned short* Fh   = Eh + (size_t)H_ * KP * T_;      // 8.39 MB
  float* part = (float*)(Fh + (size_t)H_ * KP * T_);     // 16.78 MB
  unsigned short* kprojh = (unsigned short*)(part + (size_t)B_ * H_ * TCH * KP * D_);
  unsigned short* vpTh   = kprojh + (size_t)B_ * H_ * KP * D_;   // 2.10 MB each
  unsigned short* yh = xh;                               // x dead after qkv GEMM

  // 0) casts / transposes
  cast_bf16<<<(M_ * C_ / 4 + 255) / 256, 256, 0, stream>>>(x, xh, M_ * C_ / 4);
  cast_bf16<<<(H_ * KP * T_ / 4 + 255) / 256, 256, 0, stream>>>(E, Eh, H_ * KP * T_ / 4);
  cast_bf16<<<(H_ * KP * T_ / 4 + 255) / 256, 256, 0, stream>>>(F, Fh, H_ * KP * T_ / 4);
  cast_tr<<<dim3(C3 / 32, C_ / 32), 256, 0, stream>>>(W_attn, WaT, C_, C3);
  cast_tr<<<dim3(C_ / 32, C_ / 32), 256, 0, stream>>>(W_proj, WpT, C_, C_);

  // 1) qkv = x @ W_attn + b_attn  (fused, N=3072, bf16 out) — 128x256, 2/CU
  gemm128<true><<<dim3((M_ / 128) * (C3 / 256)), 512, 0, stream>>>(
      xh, WaT, b_attn, nullptr, qkvh, C3);

  // 2) kproj = E @ k  (k = qkv cols [C,2C))
  proj_mfma<<<dim3(B_ * H_, TCH), 256, 0, stream>>>(Eh, qkvh + C_, C3, part);
  reduce_k<<<(B_ * H_ * KP * D_) / 256, 256, 0, stream>>>(part, kprojh);

  // 3) vpT = transpose(F @ v)  (v = qkv cols [2C,3C))
  proj_mfma<<<dim3(B_ * H_, TCH), 256, 0, stream>>>(Fh, qkvh + 2 * C_, C3, part);
  reduce_v<<<B_ * H_, 256, 0, stream>>>(part, vpTh);

  // 4) MFMA attention -> y bf16 (overwrites x region)
  attn_mfma<<<B_ * H_ * (T_ / 64), 256, 0, stream>>>(qkvh, kprojh, vpTh, yh);

  // 5) out = y @ W_proj + b_proj (fp32 out) — 128x256, 2/CU
  gemm128<false><<<dim3((M_ / 128) * (C_ / 256)), 512, 0, stream>>>(
      yh, WpT, b_proj, out, nullptr, C_);
}

// Round 6
// 396.864 us; speedup vs baseline: 1.0704x; 1.0704x over previous
//
#include <hip/hip_runtime.h>
#include <math.h>

// LinformerAttention on MI355X — Round 12:
//  * GEMM: revert to R9 exactly (256x256 8-phase, fragment-linear LDS,
//    zero bank conflicts, counted vmcnt(6)) — best measured (125 us qkv).
//  * proj_full: fused projection (no part buffer, no reduce kernels):
//    grid (bh, kk-half); full-T accumulation in-register; direct bf16 write
//    (template TRANS: vpT transposed, ushort4-packed).
//  * attn2: 4 Q-tiles per block; Kp/Vp staged ONCE (separate LDS regions,
//    single barrier); Q fragments direct from global; wave-private Ps;
//    zero barriers in the tile loop; inv folded into P pre-pack.
//  * Launch fusion: 7 dispatches (cast3, tr2, qkv, projK, projV, attn, out).
// B=8 T=2048 C=1024 H=16 D=64 Kproj=128. ws ~147 MB.

constexpr int B_ = 8, T_ = 2048, C_ = 1024, H_ = 16, D_ = 64, KP = 128;
constexpr int M_ = B_ * T_;            // 16384
constexpr int C3 = 3 * C_;             // 3072
constexpr int K_ = C_;                 // GEMM K = 1024
constexpr int NT = K_ / 64;            // 16 K-tiles of 64

typedef __attribute__((ext_vector_type(8))) short bf16x8;   // 8 bf16 = 4 VGPR
typedef __attribute__((ext_vector_type(4))) float f32x4;

__device__ __forceinline__ unsigned short f2bf(float f) {
  unsigned u = __builtin_bit_cast(unsigned, f);
  u += 0x7FFFu + ((u >> 16) & 1u);     // round-to-nearest-even
  return (unsigned short)(u >> 16);
}

#define GLOAD_LDS16(gptr, lptr)                                                \
  __builtin_amdgcn_global_load_lds(                                            \
      (const __attribute__((address_space(1))) void*)(gptr),                   \
      (__attribute__((address_space(3))) void*)(lptr), 16, 0, 0)

// ---------------------------------------------------------------------------
// Fused fp32 -> bf16 cast for x, E, F (one launch).
// ---------------------------------------------------------------------------
__global__ __launch_bounds__(256) void cast3(
    const float* __restrict__ x, const float* __restrict__ E,
    const float* __restrict__ F, unsigned short* __restrict__ xh,
    unsigned short* __restrict__ Eh, unsigned short* __restrict__ Fh)
{
  constexpr int n4x = M_ * C_ / 4;          // 4,194,304
  constexpr int n4e = H_ * KP * T_ / 4;     // 1,048,576
  const int i = blockIdx.x * 256 + threadIdx.x;
  const float* src; unsigned short* dst; int j;
  if (i < n4x)            { src = x; dst = xh; j = i; }
  else if (i < n4x + n4e) { src = E; dst = Eh; j = i - n4x; }
  else                    { src = F; dst = Fh; j = i - n4x - n4e; }
  const float4 v = reinterpret_cast<const float4*>(src)[j];
  ushort4 h;
  h.x = f2bf(v.x); h.y = f2bf(v.y); h.z = f2bf(v.z); h.w = f2bf(v.w);
  reinterpret_cast<ushort4*>(dst)[j] = h;
}

// ---------------------------------------------------------------------------
// Fused transpose+bf16 for W_attn and W_proj (one launch, flat grid).
// ---------------------------------------------------------------------------
__global__ __launch_bounds__(256) void cast_tr2(
    const float* __restrict__ Wa, unsigned short* __restrict__ WaT,
    const float* __restrict__ Wp, unsigned short* __restrict__ WpT)
{
  __shared__ float tile[32][33];
  const float* W; unsigned short* Tb; int bx, by, rows, cols;
  const int flat = blockIdx.x;
  if (flat < 3072) { W = Wa; Tb = WaT; bx = flat % 96; by = flat / 96;
                     rows = C_; cols = C3; }
  else             { const int f2 = flat - 3072;
                     W = Wp; Tb = WpT; bx = f2 % 32; by = f2 / 32;
                     rows = C_; cols = C_; }
  const int c0 = bx * 32, r0 = by * 32;
  const int tx = threadIdx.x & 31, ty = threadIdx.x >> 5;   // ty 0..7
  #pragma unroll
  for (int i = 0; i < 4; ++i)
    tile[ty + i * 8][tx] = W[(size_t)(r0 + ty + i * 8) * cols + c0 + tx];
  __syncthreads();
  #pragma unroll
  for (int i = 0; i < 4; ++i) {
    const int cr = ty + i * 8;
    Tb[(size_t)(c0 + cr) * rows + r0 + tx] = f2bf(tile[tx][cr]);
  }
}

// ---------------------------------------------------------------------------
// 256x256 8-phase GEMM (R9 exact): C(16384 x ldc) = A(MxK) @ BT^T + bias.
// Fragment-linear LDS (zero bank conflicts), counted vmcnt(6), setprio,
// XCD swizzle. See R9 notes. 512 thr = 8 waves (2Mx4N), 128 KiB LDS.
// ---------------------------------------------------------------------------
template <bool BFOUT>
__global__ __launch_bounds__(512, 2) void gemm256(
    const unsigned short* __restrict__ A, const unsigned short* __restrict__ BT,
    const float* __restrict__ bias, float* __restrict__ Cf,
    unsigned short* __restrict__ Cb, int ldc)
{
  __shared__ __attribute__((aligned(16))) char lds[131072];

  const int tid  = threadIdx.x;
  const int lane = tid & 63;
  const int w    = tid >> 6;           // 0..7
  const int wr   = w >> 2;             // 0..1 (M)
  const int wc   = w & 3;              // 0..3 (N)
  const int col  = lane & 15;
  const int quad = lane >> 4;

  const int ntx = ldc >> 8;
  int wg = blockIdx.x;
  wg = (wg & 7) * (gridDim.x >> 3) + (wg >> 3);
  const int bx = wg % ntx, by = wg / ntx;
  const int m0 = by << 8, n0 = bx << 8;

  const int kq   = quad * 8;                 // k sub-offset (bf16 elems)
  const int rowL = w * 16 + col;             // logical lds-row 0..127
  const int mOff = (rowL >> 6) * 128 + (rowL & 63);
  const int nOff = (rowL >> 5) * 64 + (rowL & 31);
  const int dstO = w * 2048 + lane * 16;     // + l*1024

#define STAGE_A(H, KT0, BUFSEL)                                                \
  { const int kb_ = (KT0) * 64 + kq;                                           \
    _Pragma("unroll")                                                          \
    for (int l = 0; l < 2; ++l)                                                \
      GLOAD_LDS16(A + (size_t)(m0 + mOff + (H) * 64) * K_ + kb_ + l * 32,      \
                  lds + (BUFSEL) * 65536 + (H) * 16384 + dstO + l * 1024); }

#define STAGE_B(H, KT0, BUFSEL)                                                \
  { const int kb_ = (KT0) * 64 + kq;                                           \
    _Pragma("unroll")                                                          \
    for (int l = 0; l < 2; ++l)                                                \
      GLOAD_LDS16(BT + (size_t)(n0 + nOff + (H) * 32) * K_ + kb_ + l * 32,     \
                  lds + (BUFSEL) * 65536 + 32768 + (H) * 16384 + dstO +        \
                      l * 1024); }

  const int laneB = lane * 16;
  const int aB0 = wr * 8192 + laneB;           // A half 0
  const int aB1 = 16384 + aB0;                 // A half 1
  const int bB0 = 32768 + wc * 4096 + laneB;   // B half 0
  const int bB1 = 16384 + bB0;                 // B half 1

  f32x4 acc[8][4];
  #pragma unroll
  for (int a = 0; a < 8; ++a)
    #pragma unroll
    for (int c = 0; c < 4; ++c)
      acc[a][c] = (f32x4){0.f, 0.f, 0.f, 0.f};

  bf16x8 av[4][2], b0v[2][2], b1v[2][2];

#define MFMA_Q(QM, QN, BV)                                                     \
  __builtin_amdgcn_s_setprio(1);                                               \
  _Pragma("unroll")                                                            \
  for (int j = 0; j < 2; ++j)                                                  \
    _Pragma("unroll")                                                          \
    for (int ks = 0; ks < 2; ++ks)                                             \
      _Pragma("unroll")                                                        \
      for (int i = 0; i < 4; ++i)                                              \
        acc[(QM) * 4 + i][(QN) * 2 + j] =                                      \
            __builtin_amdgcn_mfma_f32_16x16x32_bf16(                           \
                av[i][ks], BV[j][ks], acc[(QM) * 4 + i][(QN) * 2 + j], 0, 0, 0);\
  __builtin_amdgcn_s_setprio(0);

  STAGE_A(0, 0, 0);
  STAGE_B(0, 0, 0);
  STAGE_B(1, 0, 0);
  STAGE_A(1, 0, 0);
  asm volatile("s_waitcnt vmcnt(4)" ::: "memory");
  STAGE_A(0, 1, 1);
  STAGE_B(0, 1, 1);
  STAGE_B(1, 1, 1);
  asm volatile("s_waitcnt vmcnt(6)" ::: "memory");
  __builtin_amdgcn_s_barrier();

#define TILE(KT, CUR)                                                          \
  {                                                                            \
    const char* cb = lds + (CUR) * 65536;                                      \
    /* phase 1: quadrant (0,0); 12 ds_read; stage A1(t+1) */                   \
    _Pragma("unroll")                                                          \
    for (int i = 0; i < 4; ++i)                                                \
      _Pragma("unroll")                                                        \
      for (int ks = 0; ks < 2; ++ks)                                           \
        av[i][ks] = *reinterpret_cast<const bf16x8*>(                          \
            cb + aB0 + i * 2048 + ks * 1024);                                  \
    _Pragma("unroll")                                                          \
    for (int j = 0; j < 2; ++j)                                                \
      _Pragma("unroll")                                                        \
      for (int ks = 0; ks < 2; ++ks)                                           \
        b0v[j][ks] = *reinterpret_cast<const bf16x8*>(                         \
            cb + bB0 + j * 2048 + ks * 1024);                                  \
    if ((KT) + 1 < NT) { STAGE_A(1, (KT) + 1, (CUR) ^ 1); }                    \
    asm volatile("s_waitcnt lgkmcnt(8)" ::: "memory");                         \
    __builtin_amdgcn_s_barrier();                                              \
    asm volatile("s_waitcnt lgkmcnt(0)" ::: "memory");                         \
    __builtin_amdgcn_sched_barrier(0);                                         \
    MFMA_Q(0, 0, b0v);                                                         \
    __builtin_amdgcn_s_barrier();                                              \
    /* phase 2: quadrant (0,1); 4 ds_read; stage A0(t+2) */                    \
    _Pragma("unroll")                                                          \
    for (int j = 0; j < 2; ++j)                                                \
      _Pragma("unroll")                                                        \
      for (int ks = 0; ks < 2; ++ks)                                           \
        b1v[j][ks] = *reinterpret_cast<const bf16x8*>(                         \
            cb + bB1 + j * 2048 + ks * 1024);                                  \
    if ((KT) + 2 < NT) { STAGE_A(0, (KT) + 2, (CUR)); }                        \
    __builtin_amdgcn_s_barrier();                                              \
    asm volatile("s_waitcnt lgkmcnt(0)" ::: "memory");                         \
    __builtin_amdgcn_sched_barrier(0);                                         \
    MFMA_Q(0, 1, b1v);                                                         \
    __builtin_amdgcn_s_barrier();                                              \
    /* phase 3: quadrant (1,1); 8 ds_read; stage B0(t+2) */                    \
    _Pragma("unroll")                                                          \
    for (int i = 0; i < 4; ++i)                                                \
      _Pragma("unroll")                                                        \
      for (int ks = 0; ks < 2; ++ks)                                           \
        av[i][ks] = *reinterpret_cast<const bf16x8*>(                          \
            cb + aB1 + i * 2048 + ks * 1024);                                  \
    if ((KT) + 2 < NT) { STAGE_B(0, (KT) + 2, (CUR)); }                        \
    __builtin_amdgcn_s_barrier();                                              \
    asm volatile("s_waitcnt lgkmcnt(0)" ::: "memory");                         \
    __builtin_amdgcn_sched_barrier(0);                                         \
    MFMA_Q(1, 1, b1v);                                                         \
    __builtin_amdgcn_s_barrier();                                              \
    /* phase 4: quadrant (1,0); 0 ds_read; stage B1(t+2); boundary vmcnt */    \
    if ((KT) + 2 < NT) { STAGE_B(1, (KT) + 2, (CUR)); }                        \
    __builtin_amdgcn_s_barrier();                                              \
    __builtin_amdgcn_sched_barrier(0);                                         \
    MFMA_Q(1, 0, b0v);                                                         \
    if ((KT) < NT - 2) {                                                       \
      asm volatile("s_waitcnt vmcnt(6)" ::: "memory");                         \
    } else if ((KT) == NT - 2) {                                               \
      asm volatile("s_waitcnt vmcnt(0)" ::: "memory");                         \
    }                                                                          \
    __builtin_amdgcn_s_barrier();                                              \
  }

  for (int kt = 0; kt < NT; kt += 2) {
    TILE(kt, 0);
    TILE(kt + 1, 1);
  }
#undef TILE
#undef MFMA_Q
#undef STAGE_A
#undef STAGE_B

  #pragma unroll
  for (int a = 0; a < 8; ++a) {
    const int r = m0 + wr * 128 + (a >> 2) * 64 + (a & 3) * 16 + quad * 4;
    #pragma unroll
    for (int c = 0; c < 4; ++c) {
      const int cc = n0 + wc * 64 + (c >> 1) * 32 + (c & 1) * 16 + col;
      const float bv = bias[cc];
      #pragma unroll
      for (int rg = 0; rg < 4; ++rg) {
        const float v = acc[a][c][rg] + bv;
        const size_t o = (size_t)(r + rg) * ldc + cc;
        if constexpr (BFOUT) Cb[o] = f2bf(v);
        else Cf[o] = v;
      }
    }
  }
}

// ---------------------------------------------------------------------------
// proj_full: fused projection, full-T accumulation, direct bf16 output.
// grid (bh=128, kh=2), 256 thr (4 waves). Block computes 64 kk x 64 d:
//   out[kk][d] = sum_{t=0..2047} Eh[h][kh*64+kk][t] * kb[b*T+t][h*64+d]
// TRANS=false: kprojh[bh][kk][d] (kk global = kh*64+kkLocal)
// TRANS=true : vpTh[bh][d][kkGlobal] (ushort4-packed over 4 consecutive kk)
// ---------------------------------------------------------------------------
template <bool TRANS>
__global__ __launch_bounds__(256) void proj_full(
    const unsigned short* __restrict__ Eh, const unsigned short* __restrict__ kb,
    unsigned short* __restrict__ outp)
{
  __shared__ unsigned short sE[64 * 72];           // 9.0 KB
  __shared__ unsigned short sK[D_ * 72];           // 9.0 KB

  const int bh = blockIdx.x;
  const int kh = blockIdx.y;
  const int b = bh >> 4, h = bh & 15;
  const int tid = threadIdx.x;
  const int lane = tid & 63;
  const int w = tid >> 6;             // 0..3
  const int col = lane & 15;
  const int quad = lane >> 4;
  const int tq = tid >> 4;            // 0..15 -> t-base tq*4
  const int dq = tid & 15;            // 0..15 -> d-base dq*4

  f32x4 acc[4];
  #pragma unroll
  for (int j = 0; j < 4; ++j) acc[j] = (f32x4){0.f, 0.f, 0.f, 0.f};

  for (int s = 0; s < 32; ++s) {
    const int t0 = s * 64;
    // stage E rows kh*64+kk (64 rows x 64 t), pitch 72
    #pragma unroll
    for (int l = 0; l < 2; ++l) {
      const int idx = l * 256 + tid;
      const int kk = idx >> 3, seg = idx & 7;
      *reinterpret_cast<uint4*>(sE + kk * 72 + seg * 8) =
          *reinterpret_cast<const uint4*>(
              Eh + (size_t)(h * KP + kh * 64 + kk) * T_ + t0 + seg * 8);
    }
    { // stage k-tile transposed to sK[d][t] pitch 72
      const size_t gbase = (size_t)(b * T_ + t0 + tq * 4) * C3 + h * D_ + dq * 4;
      ushort4 r[4];
      #pragma unroll
      for (int rr = 0; rr < 4; ++rr)
        r[rr] = *reinterpret_cast<const ushort4*>(kb + gbase + (size_t)rr * C3);
      #pragma unroll
      for (int c = 0; c < 4; ++c) {
        ushort4 t;
        t.x = (&r[0].x)[c]; t.y = (&r[1].x)[c];
        t.z = (&r[2].x)[c]; t.w = (&r[3].x)[c];
        *reinterpret_cast<ushort4*>(sK + (dq * 4 + c) * 72 + tq * 4) = t;
      }
    }
    __syncthreads();

    bf16x8 av[2];
    #pragma unroll
    for (int ks = 0; ks < 2; ++ks)
      av[ks] = *reinterpret_cast<const bf16x8*>(
          sE + (w * 16 + col) * 72 + ks * 32 + quad * 8);
    #pragma unroll
    for (int j = 0; j < 4; ++j)
      #pragma unroll
      for (int ks = 0; ks < 2; ++ks) {
        const bf16x8 bv = *reinterpret_cast<const bf16x8*>(
            sK + (j * 16 + col) * 72 + ks * 32 + quad * 8);
        acc[j] = __builtin_amdgcn_mfma_f32_16x16x32_bf16(av[ks], bv, acc[j], 0, 0, 0);
      }
    __syncthreads();
  }

  // C/D: row (kk-local) = quad*4+rg, col (d) = j*16+col
  const int kkb = kh * 64 + w * 16 + quad * 4;     // global kk base (mult of 4)
  if constexpr (!TRANS) {
    unsigned short* op = outp + (size_t)bh * 8192;   // [kk][64 d]
    #pragma unroll
    for (int j = 0; j < 4; ++j) {
      const int d = j * 16 + col;
      #pragma unroll
      for (int rg = 0; rg < 4; ++rg)
        op[(kkb + rg) * D_ + d] = f2bf(acc[j][rg]);
    }
  } else {
    unsigned short* op = outp + (size_t)bh * 8192;   // [d][128 kk]
    #pragma unroll
    for (int j = 0; j < 4; ++j) {
      const int d = j * 16 + col;
      ushort4 hp;
      hp.x = f2bf(acc[j][0]); hp.y = f2bf(acc[j][1]);
      hp.z = f2bf(acc[j][2]); hp.w = f2bf(acc[j][3]);
      *reinterpret_cast<ushort4*>(op + d * KP + kkb) = hp;
    }
  }
}

// ---------------------------------------------------------------------------
// attn2: 4 Q-tiles (256 t) per block. Kp/Vp staged once (separate regions,
// one barrier); Q frags direct from global; wave-private Ps; no loop barriers;
// inv folded into P before bf16 pack.
// grid = bh*8 = 1024, 256 thr (4 waves).
// ---------------------------------------------------------------------------
__global__ __launch_bounds__(256) void attn2(
    const unsigned short* __restrict__ qkv, const unsigned short* __restrict__ kprojh,
    const unsigned short* __restrict__ vpTh, unsigned short* __restrict__ yh)
{
  // LDS: Kp[128][72] @0 (18432) | Vh[64][136] @18432 (17408) |
  //      Ps[64][136] @35840 (17408)  -> total 53248 B
  __shared__ __attribute__((aligned(16))) char lds[53248];
  unsigned short* Kp = (unsigned short*)(lds);
  unsigned short* Vh = (unsigned short*)(lds + 18432);
  unsigned short* Ps = (unsigned short*)(lds + 35840);

  const int tid  = threadIdx.x;
  const int lane = tid & 63;
  const int w    = tid >> 6;
  const int col  = lane & 15;
  const int quad = lane >> 4;
  const int bh   = blockIdx.x >> 3;
  const int tcb  = blockIdx.x & 7;
  const int b = bh >> 4, h = bh & 15;
  const int tBase = tcb * 256;

  { // stage Kp (pitch 72) and Vh (pitch 136) once
    const unsigned short* kg = kprojh + (size_t)bh * 8192;
    #pragma unroll
    for (int l = 0; l < 8; ++l) {
      const int idx = l * 256 + tid;
      const int kk = idx >> 4, dc = (idx & 15) << 2;
      *reinterpret_cast<ushort4*>(Kp + kk * 72 + dc) =
          *reinterpret_cast<const ushort4*>(kg + kk * 64 + dc);
    }
    const unsigned short* vg = vpTh + (size_t)bh * 8192;
    #pragma unroll
    for (int l = 0; l < 8; ++l) {
      const int idx = l * 256 + tid;
      const int d = idx >> 5, kc = (idx & 31) << 2;
      *reinterpret_cast<ushort4*>(Vh + d * 136 + kc) =
          *reinterpret_cast<const ushort4*>(vg + d * 128 + kc);
    }
  }
  __syncthreads();

  for (int tc = 0; tc < 4; ++tc) {
    const int t0 = tBase + tc * 64;

    // Q fragments direct from global: row t0 + w*16 + col, k = ks*32+quad*8
    const unsigned short* qg =
        qkv + (size_t)(b * T_ + t0 + w * 16 + col) * C3 + h * D_;
    bf16x8 bq[2];
    #pragma unroll
    for (int ks = 0; ks < 2; ++ks)
      bq[ks] = *reinterpret_cast<const bf16x8*>(qg + ks * 32 + quad * 8);

    // S^T = Kp(A) @ Q^T(B): m=kk (8 tiles), n=t (wave strip), k=d (2 steps)
    f32x4 s[8];
    #pragma unroll
    for (int i = 0; i < 8; ++i) s[i] = (f32x4){0.f, 0.f, 0.f, 0.f};
    #pragma unroll
    for (int i = 0; i < 8; ++i)
      #pragma unroll
      for (int ks = 0; ks < 2; ++ks) {
        const bf16x8 a = *reinterpret_cast<const bf16x8*>(
            Kp + (i * 16 + col) * 72 + ks * 32 + quad * 8);
        s[i] = __builtin_amdgcn_mfma_f32_16x16x32_bf16(a, bq[ks], s[i], 0, 0, 0);
      }

    // softmax over kk (row t = w*16+col), wave-local
    float mx = -3.0e38f;
    #pragma unroll
    for (int i = 0; i < 8; ++i)
      #pragma unroll
      for (int rg = 0; rg < 4; ++rg) {
        s[i][rg] *= 0.125f;
        mx = fmaxf(mx, s[i][rg]);
      }
    mx = fmaxf(mx, __shfl_xor(mx, 16));
    mx = fmaxf(mx, __shfl_xor(mx, 32));
    float sum = 0.f;
    #pragma unroll
    for (int i = 0; i < 8; ++i)
      #pragma unroll
      for (int rg = 0; rg < 4; ++rg) {
        const float e = __expf(s[i][rg] - mx);
        s[i][rg] = e;
        sum += e;
      }
    sum += __shfl_xor(sum, 16);
    sum += __shfl_xor(sum, 32);
    const float inv = 1.f / sum;

    // P (scaled by inv) -> Ps, wave-private rows
    #pragma unroll
    for (int i = 0; i < 8; ++i) {
      ushort4 hp;
      hp.x = f2bf(s[i][0] * inv); hp.y = f2bf(s[i][1] * inv);
      hp.z = f2bf(s[i][2] * inv); hp.w = f2bf(s[i][3] * inv);
      *reinterpret_cast<ushort4*>(Ps + (w * 16 + col) * 136 + i * 16 + quad * 4) = hp;
    }

    // y = P(A) @ V(B): m=t (wave strip), n=d (4 tiles), k=kk (4 steps)
    f32x4 y[4];
    #pragma unroll
    for (int j = 0; j < 4; ++j) y[j] = (f32x4){0.f, 0.f, 0.f, 0.f};
    bf16x8 ap[4];
    #pragma unroll
    for (int ks = 0; ks < 4; ++ks)
      ap[ks] = *reinterpret_cast<const bf16x8*>(
          Ps + (w * 16 + col) * 136 + ks * 32 + quad * 8);
    #pragma unroll
    for (int j = 0; j < 4; ++j)
      #pragma unroll
      for (int ks = 0; ks < 4; ++ks) {
        const bf16x8 bv = *reinterpret_cast<const bf16x8*>(
            Vh + (j * 16 + col) * 136 + ks * 32 + quad * 8);
        y[j] = __builtin_amdgcn_mfma_f32_16x16x32_bf16(ap[ks], bv, y[j], 0, 0, 0);
      }

    #pragma unroll
    for (int j = 0; j < 4; ++j)
      #pragma unroll
      for (int rg = 0; rg < 4; ++rg) {
        const int t = t0 + w * 16 + quad * 4 + rg;
        const int d = j * 16 + col;
        yh[(size_t)(b * T_ + t) * C_ + h * D_ + d] = f2bf(y[j][rg]);
      }
  }
}

// ---------------------------------------------------------------------------
extern "C" void kernel_launch(void* const* d_in, const int* in_sizes, int n_in,
                              void* d_out, int out_size, void* d_ws, size_t ws_size,
                              hipStream_t stream) {
  (void)in_sizes; (void)n_in; (void)out_size; (void)ws_size;
  const float* x      = (const float*)d_in[0];
  const float* W_attn = (const float*)d_in[1];
  const float* b_attn = (const float*)d_in[2];
  const float* W_proj = (const float*)d_in[3];
  const float* b_proj = (const float*)d_in[4];
  const float* E      = (const float*)d_in[5];
  const float* F      = (const float*)d_in[6];
  float* out = (float*)d_out;

  // ws regions (~147 MB peak):
  unsigned short* xh   = (unsigned short*)d_ws;          // [M][C]  33.55 MB
  unsigned short* qkvh = xh + (size_t)M_ * C_;           // [M][3C] 100.66 MB
  unsigned short* WaT  = qkvh + (size_t)M_ * C3;         // [3072][1024] 6.29 MB
  unsigned short* WpT  = WaT + (size_t)C3 * C_;          // [1024][1024] 2.10 MB
  unsigned short* Eh   = WpT + (size_t)C_ * C_;          // 8.39 MB
  unsigned short* Fh   = Eh + (size_t)H_ * KP * T_;      // 8.39 MB
  unsigned short* kprojh = Fh + (size_t)H_ * KP * T_;    // 2.10 MB
  unsigned short* vpTh   = kprojh + (size_t)B_ * H_ * KP * D_;   // 2.10 MB
  unsigned short* yh = xh;                               // x dead after qkv GEMM

  // 0) fused casts (x, E, F) + fused transposes (Wa, Wp)
  cast3<<<(M_ * C_ / 4 + 2 * (H_ * KP * T_ / 4)) / 256, 256, 0, stream>>>(
      x, E, F, xh, Eh, Fh);
  cast_tr2<<<3072 + 1024, 256, 0, stream>>>(W_attn, WaT, W_proj, WpT);

  // 1) qkv = x @ W_attn + b_attn  (fused, N=3072, bf16 out) — 8-phase 256²
  gemm256<true><<<dim3((M_ / 256) * (C3 / 256)), 512, 0, stream>>>(
      xh, WaT, b_attn, nullptr, qkvh, C3);

  // 2) kproj = E @ k (direct, no partials)
  proj_full<false><<<dim3(B_ * H_, 2), 256, 0, stream>>>(Eh, qkvh + C_, kprojh);

  // 3) vpT = transpose(F @ v) (direct, transposed write)
  proj_full<true><<<dim3(B_ * H_, 2), 256, 0, stream>>>(Fh, qkvh + 2 * C_, vpTh);

  // 4) attention -> y bf16 (overwrites x region)
  attn2<<<B_ * H_ * (T_ / 256), 256, 0, stream>>>(qkvh, kprojh, vpTh, yh);

  // 5) out = y @ W_proj + b_proj (fp32 out) — 8-phase 256²
  gemm256<false><<<dim3((M_ / 256) * (C_ / 256)), 512, 0, stream>>>(
      yh, WpT, b_proj, out, nullptr, C_);
}